// Round 9
// baseline (472.146 us; speedup 1.0000x reference)
//
#include <hip/hip_runtime.h>
#include <hip/hip_bf16.h>

#define N_NODES 100000
#define N_EDGES 1600000
#define IN_DIM  128
#define HID     64
#define CAP_N   64         // padded per-NODE capacity (avg degree 16, P(deg>=64)~1e-18)
#define CNT_STRIDE 16      // one 4B counter per 64B line
#define PAIRS_LIM (N_EDGES - 1)

#define SC_EB   1024       // edges per scatter block (4/thread)
#define SC_BLOCKS ((N_EDGES + SC_EB - 1) / SC_EB)   // 1563
#define GEMM_BLOCKS ((N_NODES + 63) / 64)           // 1563
#define PREP_BLOCKS ((N_NODES + 255) / 256)         // 391

#define PITCH_IN  152      // bf16 units per LDS row for K=128 (gemm_in staging)
#define PITCH_HID 88       // bf16 units per LDS row for K=64  (agg staging)

typedef __attribute__((ext_vector_type(8))) short bf16x8;   // MFMA A/B frag (4 VGPRs)
typedef __attribute__((ext_vector_type(4))) float f32x4;    // MFMA C/D frag

__device__ inline unsigned short f2bf(float f) {
    __hip_bfloat16 b = __float2bfloat16(f);
    return *reinterpret_cast<unsigned short*>(&b);
}

// ---------------------------------------------------------------------------
// Pre-pack W matrices into B-fragment order bf16 + zero per-node counters.
// flat = (((kc*4 + nt)*4 + quad)*16 + n16)*8 + j ;  k = kc*32+quad*8+j, n = nt*16+n16
// ---------------------------------------------------------------------------
__global__ void wf_prep_kernel(const float* __restrict__ Wi,
                               const float* __restrict__ W1,
                               const float* __restrict__ W2,
                               const float* __restrict__ W3,
                               unsigned short* __restrict__ wf_in,
                               unsigned short* __restrict__ wf_hid,
                               int* __restrict__ cnt) {
    int t = blockIdx.x * 256 + threadIdx.x;
    if (t < N_NODES) cnt[(size_t)t * CNT_STRIDE] = 0;
    if (t < 8192) {  // Wi: K=128 -> kc in 0..3
        int j = t & 7, n16 = (t >> 3) & 15, quad = (t >> 7) & 3, nt = (t >> 9) & 3, kc = t >> 11;
        int k = kc * 32 + quad * 8 + j, n = nt * 16 + n16;
        wf_in[t] = f2bf(Wi[k * HID + n]);
    }
    if (t < 4096) {  // W1..W3: K=64 -> kc in 0..1
        int j = t & 7, n16 = (t >> 3) & 15, quad = (t >> 7) & 3, nt = (t >> 9) & 3, kc = t >> 11;
        int k = kc * 32 + quad * 8 + j, n = nt * 16 + n16;
        wf_hid[t]        = f2bf(W1[k * HID + n]);
        wf_hid[4096 + t] = f2bf(W2[k * HID + n]);
        wf_hid[8192 + t] = f2bf(W3[k * HID + n]);
    }
}

// ---------------------------------------------------------------------------
// FUSED prep: even blocks scatter edges into the PADDED per-node array
// (atomic/latency-bound); odd blocks run h0 = relu(x@Wi+bi) (MFMA/BW-bound).
// bid&1 interleave puts both wave types on every CU -> gemm hides in the
// scatter's latency slack (R8: saved ~18us vs separate launches).
// ---------------------------------------------------------------------------
__global__ __launch_bounds__(256) void fused_scatter_gemm_kernel(
        const int* __restrict__ src,
        const int* __restrict__ tgt,
        const float* __restrict__ ea,
        int* __restrict__ cnt,
        int2* __restrict__ binned,
        const float* __restrict__ x,
        const unsigned short* __restrict__ wf,
        const float* __restrict__ bi,
        float* __restrict__ h0,
        __hip_bfloat16* __restrict__ hbf) {
    __shared__ unsigned short sX[64 * PITCH_IN];   // 19456 B (gemm branch only)
    const int tid = threadIdx.x;

    if ((blockIdx.x & 1) == 0) {
        // ================= scatter branch =================
        const int s  = blockIdx.x >> 1;
        const int e0 = s * SC_EB;
        #pragma unroll
        for (int k = 0; k < SC_EB / 256; ++k) {
            int e = e0 + tid + k * 256;
            if (e < N_EDGES) {
                int t = tgt[e];
                int r = atomicAdd(&cnt[(size_t)t * CNT_STRIDE], 1);
                if (r < CAP_N)   // overflow guard (P ~ 1e-13)
                    binned[(size_t)t * CAP_N + r] =
                        make_int2(src[e], __float_as_int(ea[e]));
            }
        }
        return;
    }

    // ================= gemm_in branch =================
    const int row0 = (blockIdx.x >> 1) * 64;

    #pragma unroll
    for (int it = 0; it < 8; ++it) {
        int i  = tid + it * 256;
        int r  = i >> 5;        // 32 float4 per row
        int kq = i & 31;
        int rg = row0 + r;
        float4 v = (rg < N_NODES)
                 ? ((const float4*)x)[(size_t)rg * (IN_DIM / 4) + kq]
                 : make_float4(0.f, 0.f, 0.f, 0.f);
        ushort4 pk;
        pk.x = f2bf(v.x); pk.y = f2bf(v.y); pk.z = f2bf(v.z); pk.w = f2bf(v.w);
        *(ushort4*)(sX + r * PITCH_IN + kq * 4) = pk;
    }
    __syncthreads();

    const int lane = tid & 63;
    const int wid  = tid >> 6;
    const int l16  = lane & 15;
    const int q    = lane >> 4;

    f32x4 acc[4] = {{0,0,0,0},{0,0,0,0},{0,0,0,0},{0,0,0,0}};
    const bf16x8* wf8 = (const bf16x8*)wf;

    #pragma unroll
    for (int kc = 0; kc < 4; ++kc) {
        bf16x8 af = *(const bf16x8*)(sX + (wid * 16 + l16) * PITCH_IN + kc * 32 + q * 8);
        #pragma unroll
        for (int nt = 0; nt < 4; ++nt) {
            bf16x8 bfr = wf8[((kc * 4 + nt) * 4 + q) * 16 + l16];
            acc[nt] = __builtin_amdgcn_mfma_f32_16x16x32_bf16(af, bfr, acc[nt], 0, 0, 0);
        }
    }

    // Epilogue: C/D layout col = lane&15, row = quad*4 + reg  [m89]
    #pragma unroll
    for (int nt = 0; nt < 4; ++nt) {
        float bb = bi[nt * 16 + l16];
        #pragma unroll
        for (int reg = 0; reg < 4; ++reg) {
            int rg = row0 + wid * 16 + q * 4 + reg;
            if (rg < N_NODES) {
                float v = fmaxf(acc[nt][reg] + bb, 0.0f);
                h0 [(size_t)rg * HID + nt * 16 + l16] = v;
                hbf[(size_t)rg * HID + nt * 16 + l16] = __float2bfloat16(v);
            }
        }
    }
}

// ---------------------------------------------------------------------------
// Compaction bridge A: per-256-node block sums of clamped counts.
// ---------------------------------------------------------------------------
__global__ __launch_bounds__(256) void csr_partial_kernel(
        const int* __restrict__ cnt, int* __restrict__ bsum) {
    __shared__ int s[4];
    int t = blockIdx.x * 256 + threadIdx.x;
    int v = (t < N_NODES) ? min(cnt[(size_t)t * CNT_STRIDE], CAP_N) : 0;
    #pragma unroll
    for (int d = 1; d < 64; d <<= 1) v += __shfl_xor(v, d);
    if ((threadIdx.x & 63) == 0) s[threadIdx.x >> 6] = v;
    __syncthreads();
    if (threadIdx.x == 0) bsum[blockIdx.x] = s[0] + s[1] + s[2] + s[3];
}

// ---------------------------------------------------------------------------
// Compaction bridge B: exclusive scan of the 391 block sums (one block).
// ---------------------------------------------------------------------------
__global__ void csr_scan_kernel(const int* __restrict__ bsum,
                                int* __restrict__ boffs) {
    __shared__ int s[512];
    const int tid = threadIdx.x;
    int v = (tid < PREP_BLOCKS) ? bsum[tid] : 0;
    s[tid] = v;
    __syncthreads();
    for (int off = 1; off < 512; off <<= 1) {
        int t = (tid >= off) ? s[tid - off] : 0;
        __syncthreads();
        s[tid] += t;
        __syncthreads();
    }
    if (tid < PREP_BLOCKS) boffs[tid] = s[tid] - v;
}

// ---------------------------------------------------------------------------
// Compaction bridge C: per-node offsets (block scan + boffs) and coalesced
// copy of each node's valid pairs from the padded region into compact CSR.
// 16-lane groups copy one node at a time: 128B contiguous read & write.
// ---------------------------------------------------------------------------
__global__ __launch_bounds__(256) void csr_compact_kernel(
        const int* __restrict__ cnt,
        const int* __restrict__ boffs,
        const int2* __restrict__ binned,
        int* __restrict__ offs,
        int* __restrict__ counts,
        int2* __restrict__ pairs) {
    __shared__ int soff[256], scnt[256];
    __shared__ int wsum[4];
    const int b = blockIdx.x, tid = threadIdx.x;
    const int node = b * 256 + tid;
    int v = (node < N_NODES) ? min(cnt[(size_t)node * CNT_STRIDE], CAP_N) : 0;
    const int lane = tid & 63, wid = tid >> 6;
    int sc = v;
    #pragma unroll
    for (int d = 1; d < 64; d <<= 1) {
        int t = __shfl_up(sc, d);
        if (lane >= d) sc += t;
    }
    if (lane == 63) wsum[wid] = sc;
    __syncthreads();
    int wb = 0;
    for (int w = 0; w < wid; ++w) wb += wsum[w];
    int excl = boffs[b] + wb + sc - v;
    soff[tid] = excl;
    scnt[tid] = v;
    if (node < N_NODES) { offs[node] = excl; counts[node] = v; }
    __syncthreads();

    const int g = tid >> 4, sub = tid & 15;
    for (int j = g; j < 256; j += 16) {
        int n2 = b * 256 + j;
        if (n2 < N_NODES) {
            int c = scnt[j], o = soff[j];
            const int2* sp = binned + (size_t)n2 * CAP_N;
            for (int i = sub; i < c; i += 16)
                pairs[o + i] = sp[i];
        }
    }
}

// ---------------------------------------------------------------------------
// FUSED: a = h + segment_sum(bf16(h)[src] * w) ; hnext = relu(a @ W + b).
// R4-verbatim pull-mode structure on the COMPACT CSR (proven 65.5us):
// wave-wide coalesced 64-pair prefetch for node t+1 issued before node t's
// gather; 2 edges in flight per 16-lane group; 128B coalesced row loads.
// cnt <= CAP_N = 64 by construction, so a single 64-pair chunk covers a node.
// ---------------------------------------------------------------------------
__global__ __launch_bounds__(256) void agg_gemm_kernel(
        const float* __restrict__ h,               // layer-l activations (f32)
        const __hip_bfloat16* __restrict__ hbf_in, // layer-l activations (bf16)
        const int* __restrict__ offs,
        const int* __restrict__ counts,
        const int2* __restrict__ pairs,
        const unsigned short* __restrict__ wf,     // fragment-order W (bf16 bits)
        const float* __restrict__ b,
        float* __restrict__ hnext,
        __hip_bfloat16* __restrict__ hbf_out,
        const int store_bf) {
    __shared__ unsigned short sXs[64 * PITCH_HID]; // 11264 B
    const int tid  = threadIdx.x;
    const int row0 = blockIdx.x * 64;
    const int lane = tid & 63;
    const int wid  = tid >> 6;
    const int grp  = lane >> 4;
    const int sub  = lane & 15;

    const int node0 = row0 + wid * 16;
    int beg_n = 0, cnt_n = 0;
    if (node0 < N_NODES) { beg_n = offs[node0]; cnt_n = counts[node0]; }
    int2 pl = pairs[min(beg_n + lane, PAIRS_LIM)];

    // ---- Phase 1: aggregate 16 nodes per wave into LDS (bf16) ----
    for (int t = 0; t < 16; ++t) {
        const int node = node0 + t;                // wave-uniform
        const int ccur = cnt_n;
        const int2 pl_cur = pl;
        if (t < 15) {                              // prefetch next node's pairs
            int nn = node + 1;
            if (nn < N_NODES) { beg_n = offs[nn]; cnt_n = counts[nn]; }
            else              { beg_n = 0;        cnt_n = 0; }
            pl = pairs[min(beg_n + lane, PAIRS_LIM)];
        }
        if (node < N_NODES) {
            float ax = 0.f, ay = 0.f, az = 0.f, aw = 0.f;
            const int last = ccur - 1;
            for (int i = 0; i < ccur; i += 8) {
                int e0 = i + grp;
                int e1 = i + 4 + grp;
                bool l0 = (e0 <= last);
                bool l1 = (e1 <= last);
                int s0  = __shfl(pl_cur.x, l0 ? e0 : last);
                int w0i = __shfl(pl_cur.y, l0 ? e0 : last);
                int s1  = __shfl(pl_cur.x, l1 ? e1 : last);
                int w1i = __shfl(pl_cur.y, l1 ? e1 : last);
                uint2 g0 = *(const uint2*)(hbf_in + (size_t)s0 * HID + sub * 4);
                uint2 g1 = *(const uint2*)(hbf_in + (size_t)s1 * HID + sub * 4);
                float w0 = l0 ? __int_as_float(w0i) : 0.0f;
                float w1 = l1 ? __int_as_float(w1i) : 0.0f;
                ax += w0 * __uint_as_float(g0.x << 16);
                ay += w0 * __uint_as_float(g0.x & 0xFFFF0000u);
                az += w0 * __uint_as_float(g0.y << 16);
                aw += w0 * __uint_as_float(g0.y & 0xFFFF0000u);
                ax += w1 * __uint_as_float(g1.x << 16);
                ay += w1 * __uint_as_float(g1.x & 0xFFFF0000u);
                az += w1 * __uint_as_float(g1.y << 16);
                aw += w1 * __uint_as_float(g1.y & 0xFFFF0000u);
            }
            ax += __shfl_xor(ax, 16); ay += __shfl_xor(ay, 16);
            az += __shfl_xor(az, 16); aw += __shfl_xor(aw, 16);
            ax += __shfl_xor(ax, 32); ay += __shfl_xor(ay, 32);
            az += __shfl_xor(az, 32); aw += __shfl_xor(aw, 32);
            if (grp == 0) {
                const float4 hv = *(const float4*)(h + (size_t)node * HID + sub * 4);
                ushort4 pk;
                pk.x = f2bf(hv.x + ax); pk.y = f2bf(hv.y + ay);
                pk.z = f2bf(hv.z + az); pk.w = f2bf(hv.w + aw);
                *(ushort4*)(sXs + (wid * 16 + t) * PITCH_HID + sub * 4) = pk;
            }
        } else if (grp == 0) {
            ushort4 z; z.x = 0; z.y = 0; z.z = 0; z.w = 0;
            *(ushort4*)(sXs + (wid * 16 + t) * PITCH_HID + sub * 4) = z;
        }
    }
    __syncthreads();

    // ---- Phase 2: 16x16x32 bf16 MFMA (K=64) + relu epilogue ----
    const int l16 = lane & 15;
    const int q   = lane >> 4;

    f32x4 acc[4] = {{0,0,0,0},{0,0,0,0},{0,0,0,0},{0,0,0,0}};
    const bf16x8* wf8 = (const bf16x8*)wf;

    #pragma unroll
    for (int kc = 0; kc < 2; ++kc) {
        bf16x8 af = *(const bf16x8*)(sXs + (wid * 16 + l16) * PITCH_HID + kc * 32 + q * 8);
        #pragma unroll
        for (int nt = 0; nt < 4; ++nt) {
            bf16x8 bfr = wf8[((kc * 4 + nt) * 4 + q) * 16 + l16];
            acc[nt] = __builtin_amdgcn_mfma_f32_16x16x32_bf16(af, bfr, acc[nt], 0, 0, 0);
        }
    }

    #pragma unroll
    for (int nt = 0; nt < 4; ++nt) {
        float bb = b[nt * 16 + l16];
        #pragma unroll
        for (int reg = 0; reg < 4; ++reg) {
            int rg = row0 + wid * 16 + q * 4 + reg;
            if (rg < N_NODES) {
                float v = fmaxf(acc[nt][reg] + bb, 0.0f);
                hnext[(size_t)rg * HID + nt * 16 + l16] = v;
                if (store_bf)
                    hbf_out[(size_t)rg * HID + nt * 16 + l16] = __float2bfloat16(v);
            }
        }
    }
}

extern "C" void kernel_launch(void* const* d_in, const int* in_sizes, int n_in,
                              void* d_out, int out_size, void* d_ws, size_t ws_size,
                              hipStream_t stream) {
    const float* x   = (const float*)d_in[0];
    const int*   ei  = (const int*)  d_in[1];   // (2, E): [src | tgt]
    const float* ea  = (const float*)d_in[2];
    const float* Wi  = (const float*)d_in[3];
    const float* bi  = (const float*)d_in[4];
    const float* W1  = (const float*)d_in[5];
    const float* b1  = (const float*)d_in[6];
    const float* W2  = (const float*)d_in[7];
    const float* b2  = (const float*)d_in[8];
    const float* W3  = (const float*)d_in[9];
    const float* b3  = (const float*)d_in[10];
    const float* bl[3] = { b1, b2, b3 };
    float* out = (float*)d_out;  // (4, N, HID)

    const int* src = ei;
    const int* tgt = ei + N_EDGES;

    // Workspace layout.
    int2* binned = (int2*)d_ws;                                      // N*CAP_N*8B = 51.2 MB
    int* cnt = (int*)(binned + (size_t)N_NODES * CAP_N);             // N*16 ints (6.4 MB)
    int2* pairs = (int2*)(cnt + (size_t)N_NODES * CNT_STRIDE);       // E*8B = 12.8 MB
    int* offs   = (int*)(pairs + N_EDGES);                           // N ints
    int* counts = offs + N_NODES;                                    // N ints
    int* bsum   = counts + N_NODES;                                  // 391 ints
    int* boffs  = bsum + PREP_BLOCKS;                                // 391 ints
    __hip_bfloat16* hbf0 = (__hip_bfloat16*)(boffs + PREP_BLOCKS + 2);
    __hip_bfloat16* hbf1 = hbf0 + (size_t)N_NODES * HID;             // N*HID bf16
    unsigned short* wf_in  = (unsigned short*)(hbf1 + (size_t)N_NODES * HID);
    unsigned short* wf_hid = wf_in + 8192;                           // 3 x 4096

    wf_prep_kernel<<<PREP_BLOCKS, 256, 0, stream>>>(Wi, W1, W2, W3,
                                                    wf_in, wf_hid, cnt);

    fused_scatter_gemm_kernel<<<SC_BLOCKS + GEMM_BLOCKS, 256, 0, stream>>>(
        src, tgt, ea, cnt, binned, x, wf_in, bi, out, hbf0);

    csr_partial_kernel<<<PREP_BLOCKS, 256, 0, stream>>>(cnt, bsum);
    csr_scan_kernel   <<<1, 512, 0, stream>>>(bsum, boffs);
    csr_compact_kernel<<<PREP_BLOCKS, 256, 0, stream>>>(cnt, boffs, binned,
                                                        offs, counts, pairs);

    __hip_bfloat16* hin  = hbf0;
    __hip_bfloat16* hout = hbf1;
    for (int l = 0; l < 3; ++l) {
        const float* hl = out + (size_t)l * N_NODES * HID;
        float* hn       = out + (size_t)(l + 1) * N_NODES * HID;
        agg_gemm_kernel<<<GEMM_BLOCKS, 256, 0, stream>>>(
            hl, hin, offs, counts, pairs,
            wf_hid + (size_t)l * 4096, bl[l], hn, hout, (l < 2) ? 1 : 0);
        __hip_bfloat16* t = hin; hin = hout; hout = t;
    }
}

// Round 11
// 459.102 us; speedup vs baseline: 1.0284x; 1.0284x over previous
//
#include <hip/hip_runtime.h>
#include <hip/hip_bf16.h>

#define N_NODES 100000
#define N_EDGES 1600000
#define IN_DIM  128
#define HID     64
#define CAP_N   64         // padded per-NODE capacity (avg degree 16, P(deg>=64)~1e-18)
#define CNT_STRIDE 16      // one 4B counter per 64B line

#define SC_EB   1024       // edges per scatter block (4/thread)
#define SC_BLOCKS ((N_EDGES + SC_EB - 1) / SC_EB)   // 1563
#define GEMM_BLOCKS ((N_NODES + 63) / 64)           // 1563
#define PREP_BLOCKS ((N_NODES + 255) / 256)         // 391

#define PITCH_IN  152      // bf16 units per LDS row for K=128 (gemm_in staging)
#define PITCH_HID 88       // bf16 units per LDS row for K=64  (agg staging)

typedef __attribute__((ext_vector_type(8))) short bf16x8;   // MFMA A/B frag (4 VGPRs)
typedef __attribute__((ext_vector_type(4))) float f32x4;    // MFMA C/D frag

__device__ inline unsigned short f2bf(float f) {
    __hip_bfloat16 b = __float2bfloat16(f);
    return *reinterpret_cast<unsigned short*>(&b);
}

// ---------------------------------------------------------------------------
// Pre-pack W matrices into B-fragment order bf16 + zero per-node counters.
// flat = (((kc*4 + nt)*4 + quad)*16 + n16)*8 + j ;  k = kc*32+quad*8+j, n = nt*16+n16
// ---------------------------------------------------------------------------
__global__ void wf_prep_kernel(const float* __restrict__ Wi,
                               const float* __restrict__ W1,
                               const float* __restrict__ W2,
                               const float* __restrict__ W3,
                               unsigned short* __restrict__ wf_in,
                               unsigned short* __restrict__ wf_hid,
                               int* __restrict__ cnt) {
    int t = blockIdx.x * 256 + threadIdx.x;
    if (t < N_NODES) cnt[(size_t)t * CNT_STRIDE] = 0;
    if (t < 8192) {  // Wi: K=128 -> kc in 0..3
        int j = t & 7, n16 = (t >> 3) & 15, quad = (t >> 7) & 3, nt = (t >> 9) & 3, kc = t >> 11;
        int k = kc * 32 + quad * 8 + j, n = nt * 16 + n16;
        wf_in[t] = f2bf(Wi[k * HID + n]);
    }
    if (t < 4096) {  // W1..W3: K=64 -> kc in 0..1
        int j = t & 7, n16 = (t >> 3) & 15, quad = (t >> 7) & 3, nt = (t >> 9) & 3, kc = t >> 11;
        int k = kc * 32 + quad * 8 + j, n = nt * 16 + n16;
        wf_hid[t]        = f2bf(W1[k * HID + n]);
        wf_hid[4096 + t] = f2bf(W2[k * HID + n]);
        wf_hid[8192 + t] = f2bf(W3[k * HID + n]);
    }
}

// ---------------------------------------------------------------------------
// FUSED prep: even blocks scatter edges into the PADDED per-node array
// (atomic/latency-bound); odd blocks run h0 = relu(x@Wi+bi) (MFMA/BW-bound).
// bid&1 interleave puts both wave types on every CU -> gemm hides in the
// scatter's latency slack (R8: saved ~18us vs separate launches).
// ---------------------------------------------------------------------------
__global__ __launch_bounds__(256) void fused_scatter_gemm_kernel(
        const int* __restrict__ src,
        const int* __restrict__ tgt,
        const float* __restrict__ ea,
        int* __restrict__ cnt,
        int2* __restrict__ binned,
        const float* __restrict__ x,
        const unsigned short* __restrict__ wf,
        const float* __restrict__ bi,
        float* __restrict__ h0,
        __hip_bfloat16* __restrict__ hbf) {
    __shared__ unsigned short sX[64 * PITCH_IN];   // 19456 B (gemm branch only)
    const int tid = threadIdx.x;

    if ((blockIdx.x & 1) == 0) {
        // ================= scatter branch =================
        const int s  = blockIdx.x >> 1;
        const int e0 = s * SC_EB;
        #pragma unroll
        for (int k = 0; k < SC_EB / 256; ++k) {
            int e = e0 + tid + k * 256;
            if (e < N_EDGES) {
                int t = tgt[e];
                int r = atomicAdd(&cnt[(size_t)t * CNT_STRIDE], 1);
                if (r < CAP_N)   // overflow guard (P ~ 1e-13)
                    binned[(size_t)t * CAP_N + r] =
                        make_int2(src[e], __float_as_int(ea[e]));
            }
        }
        return;
    }

    // ================= gemm_in branch =================
    const int row0 = (blockIdx.x >> 1) * 64;

    #pragma unroll
    for (int it = 0; it < 8; ++it) {
        int i  = tid + it * 256;
        int r  = i >> 5;        // 32 float4 per row
        int kq = i & 31;
        int rg = row0 + r;
        float4 v = (rg < N_NODES)
                 ? ((const float4*)x)[(size_t)rg * (IN_DIM / 4) + kq]
                 : make_float4(0.f, 0.f, 0.f, 0.f);
        ushort4 pk;
        pk.x = f2bf(v.x); pk.y = f2bf(v.y); pk.z = f2bf(v.z); pk.w = f2bf(v.w);
        *(ushort4*)(sX + r * PITCH_IN + kq * 4) = pk;
    }
    __syncthreads();

    const int lane = tid & 63;
    const int wid  = tid >> 6;
    const int l16  = lane & 15;
    const int q    = lane >> 4;

    f32x4 acc[4] = {{0,0,0,0},{0,0,0,0},{0,0,0,0},{0,0,0,0}};
    const bf16x8* wf8 = (const bf16x8*)wf;

    #pragma unroll
    for (int kc = 0; kc < 4; ++kc) {
        bf16x8 af = *(const bf16x8*)(sX + (wid * 16 + l16) * PITCH_IN + kc * 32 + q * 8);
        #pragma unroll
        for (int nt = 0; nt < 4; ++nt) {
            bf16x8 bfr = wf8[((kc * 4 + nt) * 4 + q) * 16 + l16];
            acc[nt] = __builtin_amdgcn_mfma_f32_16x16x32_bf16(af, bfr, acc[nt], 0, 0, 0);
        }
    }

    // Epilogue: C/D layout col = lane&15, row = quad*4 + reg  [m89]
    #pragma unroll
    for (int nt = 0; nt < 4; ++nt) {
        float bb = bi[nt * 16 + l16];
        #pragma unroll
        for (int reg = 0; reg < 4; ++reg) {
            int rg = row0 + wid * 16 + q * 4 + reg;
            if (rg < N_NODES) {
                float v = fmaxf(acc[nt][reg] + bb, 0.0f);
                h0 [(size_t)rg * HID + nt * 16 + l16] = v;
                hbf[(size_t)rg * HID + nt * 16 + l16] = __float2bfloat16(v);
            }
        }
    }
}

// ---------------------------------------------------------------------------
// FUSED: a = h + segment_sum(bf16(h)[src] * w) ; hnext = relu(a @ W + b).
// Pull-mode on the padded per-node edge array. CHANGE vs R8: ALL 16 of the
// wave's per-node pair-block loads are issued UPFRONT into pl[16] (fully
// unrolled -> static indexing, stays in VGPRs). In the padded layout every
// node's 512B pair region is a cold miss; 1-deep prefetch exposed ~16 serial
// miss latencies per wave (agg 88us vs 65.5us compact). 16 independent loads
// put ~30-45 line requests in flight and overlap them all.
// ---------------------------------------------------------------------------
__global__ __launch_bounds__(256) void agg_gemm_kernel(
        const float* __restrict__ h,               // layer-l activations (f32)
        const __hip_bfloat16* __restrict__ hbf_in, // layer-l activations (bf16)
        const int* __restrict__ cnt,
        const int2* __restrict__ binned,
        const unsigned short* __restrict__ wf,     // fragment-order W (bf16 bits)
        const float* __restrict__ b,
        float* __restrict__ hnext,
        __hip_bfloat16* __restrict__ hbf_out,
        const int store_bf) {
    __shared__ unsigned short sXs[64 * PITCH_HID]; // 11264 B
    const int tid  = threadIdx.x;
    const int row0 = blockIdx.x * 64;
    const int lane = tid & 63;
    const int wid  = tid >> 6;
    const int grp  = lane >> 4;
    const int sub  = lane & 15;

    const int node0 = row0 + wid * 16;

    // Counts for this wave's 16 nodes: lanes 0-15 load, shfl-broadcast.
    int cv = 0;
    {
        int nl = node0 + (lane & 15);
        if (lane < 16 && nl < N_NODES)
            cv = min(cnt[(size_t)nl * CNT_STRIDE], CAP_N);
    }

    // Issue ALL 16 pair-block loads upfront (independent misses in flight).
    // Clamped lane index: only lines covering [0,cnt) are fetched.
    int2 pl[16];
    #pragma unroll
    for (int t = 0; t < 16; ++t) {
        int cn   = __shfl(cv, t);
        int nidx = min(node0 + t, N_NODES - 1);
        pl[t] = binned[(size_t)nidx * CAP_N + min(lane, max(cn - 1, 0))];
    }

    // ---- Phase 1: aggregate 16 nodes per wave into LDS (bf16) ----
    #pragma unroll
    for (int t = 0; t < 16; ++t) {
        const int node = node0 + t;                // wave-uniform
        const int ccur = __shfl(cv, t);
        const int2 pl_cur = pl[t];
        if (node < N_NODES) {
            float ax = 0.f, ay = 0.f, az = 0.f, aw = 0.f;
            const int last = ccur - 1;
            for (int i = 0; i < ccur; i += 8) {
                int e0 = i + grp;
                int e1 = i + 4 + grp;
                bool l0 = (e0 <= last);
                bool l1 = (e1 <= last);
                int s0  = __shfl(pl_cur.x, l0 ? e0 : last);
                int w0i = __shfl(pl_cur.y, l0 ? e0 : last);
                int s1  = __shfl(pl_cur.x, l1 ? e1 : last);
                int w1i = __shfl(pl_cur.y, l1 ? e1 : last);
                uint2 g0 = *(const uint2*)(hbf_in + (size_t)s0 * HID + sub * 4);
                uint2 g1 = *(const uint2*)(hbf_in + (size_t)s1 * HID + sub * 4);
                float w0 = l0 ? __int_as_float(w0i) : 0.0f;
                float w1 = l1 ? __int_as_float(w1i) : 0.0f;
                ax += w0 * __uint_as_float(g0.x << 16);
                ay += w0 * __uint_as_float(g0.x & 0xFFFF0000u);
                az += w0 * __uint_as_float(g0.y << 16);
                aw += w0 * __uint_as_float(g0.y & 0xFFFF0000u);
                ax += w1 * __uint_as_float(g1.x << 16);
                ay += w1 * __uint_as_float(g1.x & 0xFFFF0000u);
                az += w1 * __uint_as_float(g1.y << 16);
                aw += w1 * __uint_as_float(g1.y & 0xFFFF0000u);
            }
            ax += __shfl_xor(ax, 16); ay += __shfl_xor(ay, 16);
            az += __shfl_xor(az, 16); aw += __shfl_xor(aw, 16);
            ax += __shfl_xor(ax, 32); ay += __shfl_xor(ay, 32);
            az += __shfl_xor(az, 32); aw += __shfl_xor(aw, 32);
            if (grp == 0) {
                const float4 hv = *(const float4*)(h + (size_t)node * HID + sub * 4);
                ushort4 pk;
                pk.x = f2bf(hv.x + ax); pk.y = f2bf(hv.y + ay);
                pk.z = f2bf(hv.z + az); pk.w = f2bf(hv.w + aw);
                *(ushort4*)(sXs + (wid * 16 + t) * PITCH_HID + sub * 4) = pk;
            }
        } else if (grp == 0) {
            ushort4 z; z.x = 0; z.y = 0; z.z = 0; z.w = 0;
            *(ushort4*)(sXs + (wid * 16 + t) * PITCH_HID + sub * 4) = z;
        }
    }
    __syncthreads();

    // ---- Phase 2: 16x16x32 bf16 MFMA (K=64) + relu epilogue ----
    const int l16 = lane & 15;
    const int q   = lane >> 4;

    f32x4 acc[4] = {{0,0,0,0},{0,0,0,0},{0,0,0,0},{0,0,0,0}};
    const bf16x8* wf8 = (const bf16x8*)wf;

    #pragma unroll
    for (int kc = 0; kc < 2; ++kc) {
        bf16x8 af = *(const bf16x8*)(sXs + (wid * 16 + l16) * PITCH_HID + kc * 32 + q * 8);
        #pragma unroll
        for (int nt = 0; nt < 4; ++nt) {
            bf16x8 bfr = wf8[((kc * 4 + nt) * 4 + q) * 16 + l16];
            acc[nt] = __builtin_amdgcn_mfma_f32_16x16x32_bf16(af, bfr, acc[nt], 0, 0, 0);
        }
    }

    #pragma unroll
    for (int nt = 0; nt < 4; ++nt) {
        float bb = b[nt * 16 + l16];
        #pragma unroll
        for (int reg = 0; reg < 4; ++reg) {
            int rg = row0 + wid * 16 + q * 4 + reg;
            if (rg < N_NODES) {
                float v = fmaxf(acc[nt][reg] + bb, 0.0f);
                hnext[(size_t)rg * HID + nt * 16 + l16] = v;
                if (store_bf)
                    hbf_out[(size_t)rg * HID + nt * 16 + l16] = __float2bfloat16(v);
            }
        }
    }
}

extern "C" void kernel_launch(void* const* d_in, const int* in_sizes, int n_in,
                              void* d_out, int out_size, void* d_ws, size_t ws_size,
                              hipStream_t stream) {
    const float* x   = (const float*)d_in[0];
    const int*   ei  = (const int*)  d_in[1];   // (2, E): [src | tgt]
    const float* ea  = (const float*)d_in[2];
    const float* Wi  = (const float*)d_in[3];
    const float* bi  = (const float*)d_in[4];
    const float* W1  = (const float*)d_in[5];
    const float* b1  = (const float*)d_in[6];
    const float* W2  = (const float*)d_in[7];
    const float* b2  = (const float*)d_in[8];
    const float* W3  = (const float*)d_in[9];
    const float* b3  = (const float*)d_in[10];
    const float* bl[3] = { b1, b2, b3 };
    float* out = (float*)d_out;  // (4, N, HID)

    const int* src = ei;
    const int* tgt = ei + N_EDGES;

    // Workspace layout (per-node padded edge array; padded counters;
    // hbf double-buffered).
    int2* binned = (int2*)d_ws;                                      // N*CAP_N*8B = 51.2 MB
    int* cnt = (int*)(binned + (size_t)N_NODES * CAP_N);             // N*16 ints (6.4 MB)
    __hip_bfloat16* hbf0 = (__hip_bfloat16*)(cnt + (size_t)N_NODES * CNT_STRIDE);
    __hip_bfloat16* hbf1 = hbf0 + (size_t)N_NODES * HID;             // N*HID bf16
    unsigned short* wf_in  = (unsigned short*)(hbf1 + (size_t)N_NODES * HID);
    unsigned short* wf_hid = wf_in + 8192;                           // 3 x 4096

    wf_prep_kernel<<<PREP_BLOCKS, 256, 0, stream>>>(Wi, W1, W2, W3,
                                                    wf_in, wf_hid, cnt);

    fused_scatter_gemm_kernel<<<SC_BLOCKS + GEMM_BLOCKS, 256, 0, stream>>>(
        src, tgt, ea, cnt, binned, x, wf_in, bi, out, hbf0);

    __hip_bfloat16* hin  = hbf0;
    __hip_bfloat16* hout = hbf1;
    for (int l = 0; l < 3; ++l) {
        const float* hl = out + (size_t)l * N_NODES * HID;
        float* hn       = out + (size_t)(l + 1) * N_NODES * HID;
        agg_gemm_kernel<<<GEMM_BLOCKS, 256, 0, stream>>>(
            hl, hin, cnt, binned,
            wf_hid + (size_t)l * 4096, bl[l], hn, hout, (l < 2) ? 1 : 0);
        __hip_bfloat16* t = hin; hin = hout; hout = t;
    }
}